// Round 1
// baseline (3837.629 us; speedup 1.0000x reference)
//
#include <hip/hip_runtime.h>
#include <math.h>

// VanillaRNN, bit-exact chain semantics (unchanged from R9):
//   * z[i] = ascending-k single FMA chain k=0..255, init 0, split across two
//     thread groups in program order with exact float LDS handoff.
//     R10: split point moved 128 -> 136 (P: k 0..135, Q: k 136..255).
//     Handoff point is arbitrary for a left-assoc chain -> bit-exact.
//   * z = ((W_hx*x_t) + chain) + bias_h, separately rounded, left-assoc
//   * tanh = Eigen/XLA fast-tanh WITH FMA (clamp 7.99881172180175781f)
//
// R10 changes — why (counter evidence):
//  1) VGPR_Count=80 with 128 live w values => w was stashed in AGPRs; plain
//     VALU can't read AGPR => v_accvgpr_read per FMA (+~1100 cyc/step,
//     matches VALUBusy inflation). amdgpu_waves_per_eu(2,2) caps occupancy
//     at what we actually get (8 waves/CU resident) so the allocator keeps
//     w in the 256 arch-VGPR budget.
//  2) 264 broadcast ds_read_b128/phase/CU * ~6.8cyc ~= 1800cyc = measured
//     phase time => LDS return pipe was a co-bottleneck. Hybrid: alternating
//     16-element blocks read h via broadcast ds_read_b128 (LDS pipe) vs
//     v_readlane from per-wave lane-resident h (VALU pipe, register-only).
//     Same float values, same ascending-k order -> bit-exact.
//  3) P=136/Q=120 rebalance: Q carries tanh+epilogue (~30 serial ops);
//     equalizes per-phase critical paths (P no longer idles at barriers).
// Schedule (unchanged): phaseA: P(col0,u) | Q(col1,u-1); phaseB: P(col1,u)
// | Q(col0,u); drain Q(col1,TT-1). Parity rp=(u&1)^1 runtime (cheap now).

#define TT 2048
#define BB 512
#define HH 256
#define CC 10
#define KP 136   // P chain length  (k = 0..135)
#define KQ 120   // Q chain length  (k = 136..255)

__device__ __forceinline__ float ref_tanhf(float x)
{
    const float a1  = 4.89352455891786e-03f;
    const float a3  = 6.37261928875436e-04f;
    const float a5  = 1.48572235717979e-05f;
    const float a7  = 5.12229709037114e-08f;
    const float a9  = -8.60467152213735e-11f;
    const float a11 = 2.00018790482477e-13f;
    const float a13 = -2.76076847742355e-16f;
    const float b0  = 4.89352518554385e-03f;
    const float b2  = 2.26843463243900e-03f;
    const float b4  = 1.18534705686654e-04f;
    const float b6  = 1.19825839466702e-06f;

    const float kClamp = 7.99881172180175781f;
    const float xc = fmaxf(fminf(x, kClamp), -kClamp);
    const float x2 = __fmul_rn(xc, xc);
    float p = fmaf(x2, a13, a11);
    p = fmaf(x2, p, a9);
    p = fmaf(x2, p, a7);
    p = fmaf(x2, p, a5);
    p = fmaf(x2, p, a3);
    p = fmaf(x2, p, a1);
    p = __fmul_rn(xc, p);
    float q = fmaf(x2, b6, b4);
    q = fmaf(x2, q, b2);
    q = fmaf(x2, q, b0);
    const float r = __fdiv_rn(p, q);
    return (fabsf(x) < 0.0004f) ? x : r;
}

__global__ __launch_bounds__(512)
__attribute__((amdgpu_waves_per_eu(2, 2)))
void rnn_fwd(const float* __restrict__ x,
             const float* __restrict__ W_hx,
             const float* __restrict__ W_hh,
             const float* __restrict__ W_ph,
             const float* __restrict__ bias_h,
             const float* __restrict__ bias_p,
             float* __restrict__ out)
{
    const int tid   = threadIdx.x;
    const int group = tid >> 8;        // 0 = P (k 0..135), 1 = Q (k 136..255)
    const int i     = tid & (HH - 1);  // hidden row
    const int l     = tid & 63;        // lane id (readlane source layout)
    const int b0    = blockIdx.x * 2;  // two batch columns per WG

    __shared__ __align__(16) float xls[2][TT];        // 16 KB
    __shared__ __align__(16) float hbuf[2][2][HH];    // [col][parity][row] 4 KB
    __shared__ __align__(16) float zpart[2][HH];      // 2 KB

    // --- stage: this thread's k-segment of W_hh row -> arch VGPRs ---
    float w[KP];
    {
        const float* __restrict__ wrow =
            W_hh + (size_t)i * HH + (group ? KP : 0);
        if (group == 0) {
#pragma unroll
            for (int k = 0; k < KP; k += 4) {
                const float4 v = *reinterpret_cast<const float4*>(wrow + k);
                w[k] = v.x; w[k + 1] = v.y; w[k + 2] = v.z; w[k + 3] = v.w;
            }
#pragma unroll
            for (int k = 0; k < KP; ++k) {
                asm volatile("" : "+v"(w[k]));   // block rematerialization
            }
        } else {
#pragma unroll
            for (int k = 0; k < KQ; k += 4) {
                const float4 v = *reinterpret_cast<const float4*>(wrow + k);
                w[k] = v.x; w[k + 1] = v.y; w[k + 2] = v.z; w[k + 3] = v.w;
            }
#pragma unroll
            for (int k = 0; k < KQ; ++k) {
                asm volatile("" : "+v"(w[k]));
            }
        }
    }

    // --- stage: x rows (2*TT contiguous floats) -> LDS, 512 threads ---
    {
        const float4* __restrict__ xsrc =
            reinterpret_cast<const float4*>(x + (size_t)b0 * TT);
        float4* __restrict__ xdst = reinterpret_cast<float4*>(&xls[0][0]);
        xdst[tid]       = xsrc[tid];
        xdst[512 + tid] = xsrc[512 + tid];
    }
    const float whx = W_hx[i];     // used by Q only
    const float bh  = bias_h[i];   // used by Q only

    // h(-1)=0 at parity 1 (step t reads (t&1)^1, writes t&1)
    hbuf[group][1][i] = 0.0f;
    __syncthreads();

// 16-element block via broadcast ds_read_b128 (LDS pipe).
// h indexes and w indexes stay in ascending chain order.
#define LDSB(J0, CNT, KS)                                                     \
    _Pragma("unroll")                                                         \
    for (int jj = 0; jj < (CNT); jj += 4) {                                   \
        const float4 h4 =                                                     \
            *reinterpret_cast<const float4*>(h + (KS) + (J0) + jj);           \
        z = fmaf(w[(J0) + jj + 0], h4.x, z);                                  \
        z = fmaf(w[(J0) + jj + 1], h4.y, z);                                  \
        z = fmaf(w[(J0) + jj + 2], h4.z, z);                                  \
        z = fmaf(w[(J0) + jj + 3], h4.w, z);                                  \
    }

// 16-element block via v_readlane from lane-resident h (VALU pipe, reg-only).
// lane index = (J0)+jj-(LOFF), compile-time constant after unroll.
#define RLB(J0, CNT, SRC, LOFF)                                               \
    _Pragma("unroll")                                                         \
    for (int jj = 0; jj < (CNT); ++jj) {                                      \
        const float hv = __int_as_float(__builtin_amdgcn_readlane(            \
            __float_as_int(SRC), (J0) + jj - (LOFF)));                        \
        z = fmaf(w[(J0) + jj], hv, z);                                        \
    }

// P half-chain: k = 0..135, init 0, store exact partial.
// hA = h[0..63] per lane, hB = h[64..127] per lane (one ds_read2_b32).
#define PBODY(COL, RP)                                                        \
    {                                                                         \
        const float* __restrict__ h = &hbuf[(COL)][(RP)][0];                  \
        const float hA = h[l];                                                \
        const float hB = h[64 + l];                                           \
        float z = 0.0f;                                                       \
        LDSB(0, 16, 0)   RLB(16, 16, hA, 0)                                   \
        LDSB(32, 16, 0)  RLB(48, 16, hA, 0)                                   \
        LDSB(64, 16, 0)  RLB(80, 16, hB, 64)                                  \
        LDSB(96, 16, 0)  RLB(112, 16, hB, 64)                                 \
        LDSB(128, 8, 0)                                                       \
        zpart[(COL)][i] = z;                                                  \
    }

// Q half-chain: resume k = 136..255 (local j = k-136), then x/bias/tanh,
// write parity RP^1. hD = h[136+l], hE = h[192+l] (one ds_read2_b32).
#define QBODY(COL, T, RP)                                                     \
    {                                                                         \
        const float* __restrict__ h = &hbuf[(COL)][(RP)][0];                  \
        const float hD = h[136 + l];                                          \
        const float hE = h[192 + l];                                          \
        float z = zpart[(COL)][i];                                            \
        LDSB(0, 16, 136)  RLB(16, 16, hD, 0)                                  \
        LDSB(32, 16, 136) RLB(48, 16, hD, 0)                                  \
        LDSB(64, 16, 136) RLB(80, 16, hE, 56)                                 \
        LDSB(96, 16, 136) RLB(112, 8, hE, 56)                                 \
        const float a0 = __fmul_rn(whx, xls[(COL)][(T)]);                     \
        z = __fadd_rn(__fadd_rn(a0, z), bh);                                  \
        hbuf[(COL)][(RP) ^ 1][i] = ref_tanhf(z);                              \
    }

    // u = 0 peeled (no Q work in phase A yet), rp = 1.
    if (group == 0) { PBODY(0, 1) }
    __syncthreads();
    if (group == 0) { PBODY(1, 1) } else { QBODY(0, 0, 1) }
    __syncthreads();

#pragma unroll 1
    for (int u = 1; u < TT; ++u) {
        const int rp = (u & 1) ^ 1;            // read parity for step u
        if (group == 0) { PBODY(0, rp) } else { QBODY(1, u - 1, rp ^ 1) }
        __syncthreads();
        if (group == 0) { PBODY(1, rp) } else { QBODY(0, u, rp) }
        __syncthreads();
    }
    // drain pipeline: col1, last step (reads parity 0, writes parity 1)
    if (group == 1) { QBODY(1, TT - 1, 0) }
    __syncthreads();

#undef QBODY
#undef PBODY
#undef RLB
#undef LDSB

    // epilogue: p[b,c] = sum_k h_T[k]*W_ph[c,k] + bias_p[c]
    // last step t = TT-1 wrote parity (TT-1)&1 = 1
    if (tid < 2 * CC) {
        const int col = tid / CC;
        const int c   = tid % CC;
        const float* __restrict__ wp = W_ph + (size_t)c * HH;
        const float* __restrict__ hf = hbuf[col][1];
        float pv = 0.0f;
#pragma unroll 8
        for (int k = 0; k < HH; ++k) {
            pv = fmaf(hf[k], wp[k], pv);
        }
        out[(size_t)(b0 + col) * CC + c] = __fadd_rn(pv, bias_p[c]);
    }
}

extern "C" void kernel_launch(void* const* d_in, const int* in_sizes, int n_in,
                              void* d_out, int out_size, void* d_ws, size_t ws_size,
                              hipStream_t stream) {
    const float* x      = (const float*)d_in[0];
    const float* W_hx   = (const float*)d_in[1];
    const float* W_hh   = (const float*)d_in[2];
    const float* W_ph   = (const float*)d_in[3];
    const float* bias_h = (const float*)d_in[4];
    const float* bias_p = (const float*)d_in[5];
    float* out = (float*)d_out;

    rnn_fwd<<<dim3(BB / 2), dim3(512), 0, stream>>>(x, W_hx, W_hh, W_ph, bias_h, bias_p, out);
}

// Round 2
// 3722.982 us; speedup vs baseline: 1.0308x; 1.0308x over previous
//
#include <hip/hip_runtime.h>
#include <math.h>

// VanillaRNN, bit-exact chain semantics (R9 ordering restored verbatim):
//   * z[i] = ascending-k single FMA chain k=0..255, init 0, split across two
//     thread groups in program order (P: k=0..127 -> exact float LDS handoff
//     -> Q: k=128..255) — identical op sequence, bit-exact.
//   * z = ((W_hx*x_t) + chain) + bias_h, separately rounded, left-assoc
//   * tanh = Eigen/XLA fast-tanh WITH FMA (clamp 7.99881172180175781f)
//
// R11 changes — why (counter evidence):
//  * R8->R9 removed ~1100 VALU cyc/step with FLAT wall clock => NOT
//    VALU-bound; LDS pipe does ~544 instrs/u-iter at measured 6.6 cyc each
//    vs ~4 cyc broadcast-return floor => LDS-bound with stall overhead.
//  * VGPR_Count=80 with 128 live w => w in AGPRs, only ~8 h-quads
//    buffered => LDS issue-wait-consume windows, not streaming.
//  * Fix: (1) pin w into AGPRs EXPLICITLY ("+a" pins) — the accvgpr_read
//    per FMA lands in the proven VALU slack; (2) body issues ALL 32 h-quad
//    ds_read_b128 up front into named float4s (~128 VGPRs freed for h),
//    so the LDS pipe streams back-to-back across 8 waves.
//  * t-loop stays unrolled x2 with literal parity/offsets (R10 regression
//    lesson: runtime parity re-adds ~1100 cyc/step of address VALU).
// Schedule (unchanged, audited): phaseA(u): P(col0,u,rp) | Q(col1,u-1,rp^1)
// [u>=1]; phaseB(u): P(col1,u,rp) | Q(col0,u,rp); epilogue Q(col1,TT-1,0);
// rp=(u&1)^1 compile-time via unroll.

#define TT 2048
#define BB 512
#define HH 256
#define CC 10
#define KH 128   // chain half-length per thread group

__device__ __forceinline__ float ref_tanhf(float x)
{
    const float a1  = 4.89352455891786e-03f;
    const float a3  = 6.37261928875436e-04f;
    const float a5  = 1.48572235717979e-05f;
    const float a7  = 5.12229709037114e-08f;
    const float a9  = -8.60467152213735e-11f;
    const float a11 = 2.00018790482477e-13f;
    const float a13 = -2.76076847742355e-16f;
    const float b0  = 4.89352518554385e-03f;
    const float b2  = 2.26843463243900e-03f;
    const float b4  = 1.18534705686654e-04f;
    const float b6  = 1.19825839466702e-06f;

    const float kClamp = 7.99881172180175781f;
    const float xc = fmaxf(fminf(x, kClamp), -kClamp);
    const float x2 = __fmul_rn(xc, xc);
    float p = fmaf(x2, a13, a11);
    p = fmaf(x2, p, a9);
    p = fmaf(x2, p, a7);
    p = fmaf(x2, p, a5);
    p = fmaf(x2, p, a3);
    p = fmaf(x2, p, a1);
    p = __fmul_rn(xc, p);
    float q = fmaf(x2, b6, b4);
    q = fmaf(x2, q, b2);
    q = fmaf(x2, q, b0);
    const float r = __fdiv_rn(p, q);
    return (fabsf(x) < 0.0004f) ? x : r;
}

__global__ __launch_bounds__(512, 2)
void rnn_fwd(const float* __restrict__ x,
             const float* __restrict__ W_hx,
             const float* __restrict__ W_hh,
             const float* __restrict__ W_ph,
             const float* __restrict__ bias_h,
             const float* __restrict__ bias_p,
             float* __restrict__ out)
{
    const int tid   = threadIdx.x;
    const int group = tid >> 8;        // 0 = P (k 0..127), 1 = Q (k 128..255)
    const int i     = tid & (HH - 1);  // hidden row
    const int b0    = blockIdx.x * 2;  // two batch columns per WG

    __shared__ __align__(16) float xls[2][TT];        // 16 KB
    __shared__ __align__(16) float hbuf[2][2][HH];    // [col][parity][row] 4 KB
    __shared__ __align__(16) float zpart[2][HH];      // 2 KB

    // --- stage: this thread's half-row of W_hh -> 128 AGPRs (explicit) ---
    float w[KH];
    const float* __restrict__ wrow = W_hh + (size_t)i * HH + group * KH;
#pragma unroll
    for (int k = 0; k < KH; k += 4) {
        const float4 v = *reinterpret_cast<const float4*>(wrow + k);
        w[k] = v.x; w[k + 1] = v.y; w[k + 2] = v.z; w[k + 3] = v.w;
    }
#pragma unroll
    for (int k = 0; k < KH; ++k) {
        asm volatile("" : "+a"(w[k]));   // pin to AGPR: frees ~128 arch VGPRs
    }                                    // for deep h-quad LDS streaming

    // --- stage: x rows (2*TT contiguous floats) -> LDS, 512 threads ---
    {
        const float4* __restrict__ xsrc =
            reinterpret_cast<const float4*>(x + (size_t)b0 * TT);
        float4* __restrict__ xdst = reinterpret_cast<float4*>(&xls[0][0]);
        xdst[tid]       = xsrc[tid];
        xdst[512 + tid] = xsrc[512 + tid];
    }
    const float whx = W_hx[i];     // used by Q only
    const float bh  = bias_h[i];   // used by Q only

    // h(-1)=0 at parity 1 (step t reads (t&1)^1, writes t&1)
    hbuf[group][1][i] = 0.0f;
    __syncthreads();

// One broadcast h-quad load into a named register quad.
#define LQ(N, OFF)                                                            \
    const float4 q##N = *reinterpret_cast<const float4*>(h + (OFF));

// All 32 quads of a 128-float half, issued back-to-back (streams LDS pipe).
#define LQALL(B)                                                              \
    LQ(0,  (B) + 0)   LQ(1,  (B) + 4)   LQ(2,  (B) + 8)   LQ(3,  (B) + 12)   \
    LQ(4,  (B) + 16)  LQ(5,  (B) + 20)  LQ(6,  (B) + 24)  LQ(7,  (B) + 28)   \
    LQ(8,  (B) + 32)  LQ(9,  (B) + 36)  LQ(10, (B) + 40)  LQ(11, (B) + 44)   \
    LQ(12, (B) + 48)  LQ(13, (B) + 52)  LQ(14, (B) + 56)  LQ(15, (B) + 60)   \
    LQ(16, (B) + 64)  LQ(17, (B) + 68)  LQ(18, (B) + 72)  LQ(19, (B) + 76)   \
    LQ(20, (B) + 80)  LQ(21, (B) + 84)  LQ(22, (B) + 88)  LQ(23, (B) + 92)   \
    LQ(24, (B) + 96)  LQ(25, (B) + 100) LQ(26, (B) + 104) LQ(27, (B) + 108)  \
    LQ(28, (B) + 112) LQ(29, (B) + 116) LQ(30, (B) + 120) LQ(31, (B) + 124)

// 4 chain FMAs from one quad; strictly ascending k order (bit-exact).
#define F4(N, K)                                                              \
    z = fmaf(w[(K)],     q##N.x, z);                                          \
    z = fmaf(w[(K) + 1], q##N.y, z);                                          \
    z = fmaf(w[(K) + 2], q##N.z, z);                                          \
    z = fmaf(w[(K) + 3], q##N.w, z);

#define FALL                                                                  \
    F4(0, 0)    F4(1, 4)    F4(2, 8)    F4(3, 12)                             \
    F4(4, 16)   F4(5, 20)   F4(6, 24)   F4(7, 28)                             \
    F4(8, 32)   F4(9, 36)   F4(10, 40)  F4(11, 44)                            \
    F4(12, 48)  F4(13, 52)  F4(14, 56)  F4(15, 60)                            \
    F4(16, 64)  F4(17, 68)  F4(18, 72)  F4(19, 76)                            \
    F4(20, 80)  F4(21, 84)  F4(22, 88)  F4(23, 92)                            \
    F4(24, 96)  F4(25, 100) F4(26, 104) F4(27, 108)                           \
    F4(28, 112) F4(29, 116) F4(30, 120) F4(31, 124)

// P half-chain: k = 0..127, init 0, store exact partial.
#define PBODY(COL, T, RP)                                                     \
    {                                                                         \
        const float* __restrict__ h = &hbuf[(COL)][(RP)][0];                  \
        LQALL(0)                                                              \
        float z = 0.0f;                                                       \
        FALL                                                                  \
        zpart[(COL)][i] = z;                                                  \
    }

// Q half-chain: resume k = 128..255, then x/bias/tanh, write parity RP^1.
// zpart read issued first (needed first); 32 h-quads stream behind it.
#define QBODY(COL, T, RP)                                                     \
    {                                                                         \
        const float* __restrict__ h = &hbuf[(COL)][(RP)][0];                  \
        float z = zpart[(COL)][i];                                            \
        LQALL(KH)                                                             \
        FALL                                                                  \
        const float a0 = __fmul_rn(whx, xls[(COL)][(T)]);                     \
        z = __fadd_rn(__fadd_rn(a0, z), bh);                                  \
        hbuf[(COL)][(RP) ^ 1][i] = ref_tanhf(z);                              \
    }

// One u-iteration with compile-time read-parity RP = (u&1)^1.
#define STEP(U, RP)                                                           \
    {                                                                         \
        if (group == 0) { PBODY(0, (U), (RP)) }                               \
        else if ((U) >= 1) { QBODY(1, (U) - 1, (RP) ^ 1) }                    \
        __syncthreads();                                                      \
        if (group == 0) { PBODY(1, (U), (RP)) }                               \
        else { QBODY(0, (U), (RP)) }                                          \
        __syncthreads();                                                      \
    }

    // u=0 peeled (resolves the u>=1 guard), then pairs with constant parity.
    STEP(0, 1)
    for (int u = 1; u + 1 < TT; u += 2) {
        STEP(u, 0)
        STEP(u + 1, 1)
    }
    STEP(TT - 1, 0)                       // u = 2047 (odd -> rp = 0)
    if (group == 1) { QBODY(1, TT - 1, 0) }   // drain pipeline: col1, last step
    __syncthreads();

#undef STEP
#undef QBODY
#undef PBODY
#undef FALL
#undef F4
#undef LQALL
#undef LQ

    // epilogue: p[b,c] = sum_k h_T[k]*W_ph[c,k] + bias_p[c]
    // last step t = TT-1 wrote parity (TT-1)&1 = 1
    if (tid < 2 * CC) {
        const int col = tid / CC;
        const int c   = tid % CC;
        const float* __restrict__ wp = W_ph + (size_t)c * HH;
        const float* __restrict__ hf = hbuf[col][1];
        float pv = 0.0f;
#pragma unroll 8
        for (int k = 0; k < HH; ++k) {
            pv = fmaf(hf[k], wp[k], pv);
        }
        out[(size_t)(b0 + col) * CC + c] = __fadd_rn(pv, bias_p[c]);
    }
}

extern "C" void kernel_launch(void* const* d_in, const int* in_sizes, int n_in,
                              void* d_out, int out_size, void* d_ws, size_t ws_size,
                              hipStream_t stream) {
    const float* x      = (const float*)d_in[0];
    const float* W_hx   = (const float*)d_in[1];
    const float* W_hh   = (const float*)d_in[2];
    const float* W_ph   = (const float*)d_in[3];
    const float* bias_h = (const float*)d_in[4];
    const float* bias_p = (const float*)d_in[5];
    float* out = (float*)d_out;

    rnn_fwd<<<dim3(BB / 2), dim3(512), 0, stream>>>(x, W_hx, W_hh, W_ph, bias_h, bias_p, out);
}